// Round 1
// baseline (560.519 us; speedup 1.0000x reference)
//
#include <hip/hip_runtime.h>

// ---------------- constants (reference is compile-time fixed) ----------------
#define T_TOK 2048
#define DM    4096
#define NH    32
#define KVH   8
#define HD    128
#define QKV_N 6144          // 4096 q + 1024 k + 1024 v
#define KOFF  4096
#define VOFF  5120
#define SCALE 0.08838834764831845f   // 128^-0.5

typedef __attribute__((ext_vector_type(8))) short  short8;   // 8 bf16 (4 VGPRs)
typedef __attribute__((ext_vector_type(4))) float  floatx4;  // MFMA acc

__device__ __forceinline__ ushort f2bf(float f) {
  union { float f; unsigned u; } x; x.f = f;
  unsigned u = x.u;
  return (ushort)((u + 0x7fffu + ((u >> 16) & 1u)) >> 16);   // RNE
}
__device__ __forceinline__ float bf2f(ushort h) {
  union { unsigned u; float f; } x; x.u = ((unsigned)h) << 16;
  return x.f;
}

// ---------------- fp32 -> bf16 cast (vectorized) ----------------
__global__ void __launch_bounds__(256) cast_bf16_kernel(const float* __restrict__ x,
                                                        ushort* __restrict__ y, int n4) {
  int i = blockIdx.x * 256 + threadIdx.x;
  if (i >= n4) return;
  float4 v = ((const float4*)x)[i];
  ushort4 o;
  o.x = f2bf(v.x); o.y = f2bf(v.y); o.z = f2bf(v.z); o.w = f2bf(v.w);
  ((ushort4*)y)[i] = o;
}

// ---------------- async global->LDS, 16B per lane ----------------
__device__ __forceinline__ void gld_lds16(const ushort* g, ushort* l) {
  __builtin_amdgcn_global_load_lds((const __attribute__((address_space(1))) unsigned int*)g,
                                   (__attribute__((address_space(3))) unsigned int*)l,
                                   16, 0, 0);
}

// ---------------- GEMM: C[m][n] = sum_k A[m][k]*B[n][k]  (both K-major, bf16) --
// mode 0: clip(+-8) -> bf16 to Cb.  mode 1: fp32 to Cf.
// block 256 thr = 4 waves (2x2 of 64x64), tile 128x128, BK=32 (m97 structure)
__global__ void __launch_bounds__(256) gemm_bt(const ushort* __restrict__ A,
                                               const ushort* __restrict__ B,
                                               ushort* __restrict__ Cb,
                                               float* __restrict__ Cf,
                                               int N, int K, int mode) {
  __shared__ ushort As[128 * 32];
  __shared__ ushort Bs[128 * 32];
  const int tid = threadIdx.x, wave = tid >> 6, lane = tid & 63;
  const int bm = blockIdx.y * 128, bn = blockIdx.x * 128;
  const int wr = (wave >> 1) * 64, wc = (wave & 1) * 64;
  const int r = lane & 15, g = lane >> 4;

  floatx4 zero = {0.f, 0.f, 0.f, 0.f};
  floatx4 acc[4][4];
#pragma unroll
  for (int mi = 0; mi < 4; mi++)
#pragma unroll
    for (int ni = 0; ni < 4; ni++) acc[mi][ni] = zero;

  // staging: wave stages 32 rows of each tile; lane -> (row=lane/4, col8=lane%4)
  const ushort* Ag = A + (size_t)(bm + wave * 32 + (lane >> 2)) * K + (lane & 3) * 8;
  const ushort* Bg = B + (size_t)(bn + wave * 32 + (lane >> 2)) * K + (lane & 3) * 8;
  ushort* Al = &As[(wave * 32) * 32];
  ushort* Bl = &Bs[(wave * 32) * 32];

  for (int k0 = 0; k0 < K; k0 += 32) {
    gld_lds16(Ag,          Al);
    gld_lds16(Ag + 16 * K, Al + 16 * 32);
    gld_lds16(Bg,          Bl);
    gld_lds16(Bg + 16 * K, Bl + 16 * 32);
    Ag += 32; Bg += 32;
    __syncthreads();                       // compiler drains vmcnt before barrier

    short8 af[4], bfr[4];
#pragma unroll
    for (int i = 0; i < 4; i++) af[i]  = *(const short8*)&As[(wr + i * 16 + r) * 32 + g * 8];
#pragma unroll
    for (int i = 0; i < 4; i++) bfr[i] = *(const short8*)&Bs[(wc + i * 16 + r) * 32 + g * 8];
#pragma unroll
    for (int mi = 0; mi < 4; mi++)
#pragma unroll
      for (int ni = 0; ni < 4; ni++)
        acc[mi][ni] = __builtin_amdgcn_mfma_f32_16x16x32_bf16(af[mi], bfr[ni], acc[mi][ni], 0, 0, 0);
    __syncthreads();
  }

  // epilogue: C/D layout col=lane&15, row=(lane>>4)*4+reg  (m89/m91 verified)
#pragma unroll
  for (int mi = 0; mi < 4; mi++)
#pragma unroll
    for (int v = 0; v < 4; v++) {
      int row = bm + wr + mi * 16 + g * 4 + v;
#pragma unroll
      for (int ni = 0; ni < 4; ni++) {
        int col = bn + wc + ni * 16 + r;
        float x = acc[mi][ni][v];
        if (mode == 0) {
          x = fminf(8.0f, fmaxf(-8.0f, x));
          Cb[(size_t)row * N + col] = f2bf(x);
        } else {
          Cf[(size_t)row * N + col] = x;
        }
      }
    }
}

// ---------------- RoPE (NeoX half-split) on q and k, q pre-scaled ----------------
// grid (10, 2048), block 256: h = bx*4 + tid/64 in [0,40), d = tid&63
__global__ void __launch_bounds__(256) rope_kernel(ushort* __restrict__ qkv,
                                                   const float* __restrict__ cosb,
                                                   const float* __restrict__ sinb) {
  int t = blockIdx.y;
  int h = blockIdx.x * 4 + (threadIdx.x >> 6);
  int d = threadIdx.x & 63;
  size_t base = (size_t)t * QKV_N + (h < NH ? h * HD : KOFF + (h - NH) * HD);
  float x1 = bf2f(qkv[base + d]);
  float x2 = bf2f(qkv[base + 64 + d]);
  float c = cosb[t * 64 + d], s = sinb[t * 64 + d];
  float y1 = x1 * c - x2 * s;
  float y2 = x2 * c + x1 * s;
  if (h < NH) { y1 *= SCALE; y2 *= SCALE; }
  qkv[base + d]      = f2bf(y1);
  qkv[base + 64 + d] = f2bf(y2);
}

// ---------------- V transpose: vt[kv][d][t] = v[t][kv][d] ----------------
__global__ void __launch_bounds__(256) vtrans_kernel(const ushort* __restrict__ qkv,
                                                     ushort* __restrict__ vt) {
  int idx = blockIdx.x * 256 + threadIdx.x;   // kv(3b) | d(7b) | t(11b)
  int t  = idx & (T_TOK - 1);
  int d  = (idx >> 11) & (HD - 1);
  int kv = idx >> 18;
  vt[idx] = qkv[(size_t)t * QKV_N + VOFF + kv * HD + d];
}

// ---------------- flash attention: block = (q-tile 64, head), 4 waves x 16 rows --
__global__ void __launch_bounds__(256) attn_kernel(const ushort* __restrict__ qkv,
                                                   const ushort* __restrict__ vt,
                                                   ushort* __restrict__ o) {
  __shared__ ushort Ks[64][136];    // +8 pad keeps 16B row alignment
  __shared__ ushort Vts[128][72];
  __shared__ ushort Ps[4][16][72];  // per-wave P round-trip (C->A layout)

  const int tid = threadIdx.x, wave = tid >> 6, lane = tid & 63;
  const int r = lane & 15, g = lane >> 4;
  const int qtile = blockIdx.x, head = blockIdx.y, kvh = head >> 2;
  const int q0 = qtile * 64;
  int s0;                                            // segment start (hardcoded cu)
  if (q0 < 512) s0 = 0; else if (q0 < 1280) s0 = 512;
  else if (q0 < 1664) s0 = 1280; else s0 = 1664;

  // Q fragments straight from global (A-layout: m=lane&15, k=(lane>>4)*8+j)
  short8 qf[4];
  const int qrow = q0 + wave * 16 + r;
#pragma unroll
  for (int ks = 0; ks < 4; ks++)
    qf[ks] = *(const short8*)&qkv[(size_t)qrow * QKV_N + head * HD + ks * 32 + g * 8];

  floatx4 zero = {0.f, 0.f, 0.f, 0.f};
  floatx4 oacc[8];
#pragma unroll
  for (int b = 0; b < 8; b++) oacc[b] = zero;
  float mrun[4] = {-1e30f, -1e30f, -1e30f, -1e30f};
  float lrun[4] = {0.f, 0.f, 0.f, 0.f};

  const size_t kcol  = (size_t)KOFF + kvh * HD;
  const size_t vbase = (size_t)kvh * HD * T_TOK;

  for (int k0 = s0; k0 < q0 + 64; k0 += 64) {
    // ---- stage K tile [64 keys][128 d] and V^T tile [128 d][64 keys] ----
    short8 kreg[4], vreg[4];
#pragma unroll
    for (int p = 0; p < 4; p++) {
      int krow = p * 16 + (tid >> 4), kc = (tid & 15) * 8;
      kreg[p] = *(const short8*)&qkv[(size_t)(k0 + krow) * QKV_N + kcol + kc];
      int vd = p * 32 + (tid >> 3), vc = (tid & 7) * 8;
      vreg[p] = *(const short8*)&vt[vbase + (size_t)vd * T_TOK + k0 + vc];
    }
    __syncthreads();   // previous iter's readers done
#pragma unroll
    for (int p = 0; p < 4; p++) {
      int krow = p * 16 + (tid >> 4), kc = (tid & 15) * 8;
      *(short8*)&Ks[krow][kc] = kreg[p];
      int vd = p * 32 + (tid >> 3), vc = (tid & 7) * 8;
      *(short8*)&Vts[vd][vc] = vreg[p];
    }
    __syncthreads();

    // ---- S = Q K^T (scale folded into Q) ----
    floatx4 sacc[4];
#pragma unroll
    for (int s = 0; s < 4; s++) sacc[s] = zero;
#pragma unroll
    for (int s = 0; s < 4; s++)
#pragma unroll
      for (int ks = 0; ks < 4; ks++) {
        short8 kf = *(const short8*)&Ks[s * 16 + r][ks * 32 + g * 8];
        sacc[s] = __builtin_amdgcn_mfma_f32_16x16x32_bf16(qf[ks], kf, sacc[s], 0, 0, 0);
      }

    // ---- causal mask (only diagonal tile needs it) ----
    const bool diag = (k0 == q0);
    float sv[4][4];
#pragma unroll
    for (int s = 0; s < 4; s++)
#pragma unroll
      for (int v = 0; v < 4; v++) {
        float x = sacc[s][v];
        if (diag) {
          int ka = k0 + s * 16 + r;            // key abs (col = lane&15)
          int qa = q0 + wave * 16 + g * 4 + v; // q   abs (row = (lane>>4)*4+reg)
          if (ka > qa) x = -1e30f;
        }
        sv[s][v] = x;
      }

    // ---- online softmax (rows live across lane&15 within each 16-lane group) --
    float rmax[4];
#pragma unroll
    for (int v = 0; v < 4; v++)
      rmax[v] = fmaxf(fmaxf(sv[0][v], sv[1][v]), fmaxf(sv[2][v], sv[3][v]));
#pragma unroll
    for (int off = 1; off < 16; off <<= 1)
#pragma unroll
      for (int v = 0; v < 4; v++)
        rmax[v] = fmaxf(rmax[v], __shfl_xor(rmax[v], off, 64));

    float newm[4], alpha[4];
#pragma unroll
    for (int v = 0; v < 4; v++) {
      newm[v]  = fmaxf(mrun[v], rmax[v]);
      alpha[v] = __expf(mrun[v] - newm[v]);
      mrun[v]  = newm[v];
    }

    float pv[4][4];
    float rsum[4] = {0.f, 0.f, 0.f, 0.f};
#pragma unroll
    for (int s = 0; s < 4; s++)
#pragma unroll
      for (int v = 0; v < 4; v++) {
        float p = __expf(sv[s][v] - newm[v]);
        pv[s][v] = p;
        rsum[v] += p;
      }
#pragma unroll
    for (int off = 1; off < 16; off <<= 1)
#pragma unroll
      for (int v = 0; v < 4; v++)
        rsum[v] += __shfl_xor(rsum[v], off, 64);
#pragma unroll
    for (int v = 0; v < 4; v++) lrun[v] = lrun[v] * alpha[v] + rsum[v];
#pragma unroll
    for (int b = 0; b < 8; b++)
#pragma unroll
      for (int v = 0; v < 4; v++) oacc[b][v] *= alpha[v];

    // ---- P: C-layout -> A-layout via per-wave LDS round trip ----
#pragma unroll
    for (int s = 0; s < 4; s++)
#pragma unroll
      for (int v = 0; v < 4; v++)
        Ps[wave][g * 4 + v][s * 16 + r] = f2bf(pv[s][v]);
    __syncthreads();   // safety (uniform trip count; also orders LDS in-wave)

    short8 pf0 = *(const short8*)&Ps[wave][r][g * 8];
    short8 pf1 = *(const short8*)&Ps[wave][r][32 + g * 8];

    // ---- O += P V  (B operand from V^T tile) ----
#pragma unroll
    for (int b = 0; b < 8; b++) {
      short8 v0 = *(const short8*)&Vts[b * 16 + r][g * 8];
      short8 v1 = *(const short8*)&Vts[b * 16 + r][32 + g * 8];
      oacc[b] = __builtin_amdgcn_mfma_f32_16x16x32_bf16(pf0, v0, oacc[b], 0, 0, 0);
      oacc[b] = __builtin_amdgcn_mfma_f32_16x16x32_bf16(pf1, v1, oacc[b], 0, 0, 0);
    }
  }

  // ---- epilogue: O /= l, write bf16 ----
  float rinv[4];
#pragma unroll
  for (int v = 0; v < 4; v++) rinv[v] = 1.0f / lrun[v];
#pragma unroll
  for (int b = 0; b < 8; b++)
#pragma unroll
    for (int v = 0; v < 4; v++) {
      int qa = q0 + wave * 16 + g * 4 + v;
      o[(size_t)qa * DM + head * HD + b * 16 + r] = f2bf(oacc[b][v] * rinv[v]);
    }
}

// ---------------- launch ----------------
extern "C" void kernel_launch(void* const* d_in, const int* in_sizes, int n_in,
                              void* d_out, int out_size, void* d_ws, size_t ws_size,
                              hipStream_t stream) {
  const float* hs   = (const float*)d_in[0];   // 2048 x 4096
  const float* wqkv = (const float*)d_in[1];   // 6144 x 4096
  const float* wo   = (const float*)d_in[2];   // 4096 x 4096
  const float* cosb = (const float*)d_in[3];   // 2048 x 64
  const float* sinb = (const float*)d_in[4];   // 2048 x 64
  float* out = (float*)d_out;                  // 2048 x 4096 fp32

  char* w = (char*)d_ws;
  ushort* h_bf   = (ushort*)(w);                  // 16,777,216 B
  ushort* wq_bf  = (ushort*)(w + 16777216);       // 50,331,648 B
  ushort* wo_bf  = (ushort*)(w + 67108864);       // 33,554,432 B
  ushort* qkv_bf = (ushort*)(w + 100663296);      // 25,165,824 B
  ushort* vt     = (ushort*)(w + 125829120);      //  4,194,304 B
  ushort* ao_bf  = (ushort*)(w + 130023424);      // 16,777,216 B  (total ~147 MB)

  cast_bf16_kernel<<<8192,  256, 0, stream>>>(hs,   h_bf,  2097152);
  cast_bf16_kernel<<<24576, 256, 0, stream>>>(wqkv, wq_bf, 6291456);
  cast_bf16_kernel<<<16384, 256, 0, stream>>>(wo,   wo_bf, 4194304);

  gemm_bt<<<dim3(48, 16), 256, 0, stream>>>(h_bf, wq_bf, qkv_bf, nullptr, QKV_N, DM, 0);
  rope_kernel<<<dim3(10, T_TOK), 256, 0, stream>>>(qkv_bf, cosb, sinb);
  vtrans_kernel<<<8192, 256, 0, stream>>>(qkv_bf, vt);
  attn_kernel<<<dim3(32, 32), 256, 0, stream>>>(qkv_bf, vt, ao_bf);
  gemm_bt<<<dim3(32, 16), 256, 0, stream>>>(ao_bf, wo_bf, nullptr, out, DM, DM, 1);
}